// Round 2
// baseline (318.055 us; speedup 1.0000x reference)
//
#include <hip/hip_runtime.h>
#include <hip/hip_bf16.h>
#include <cstdint>
#include <cstddef>

#define NTOK 32768
#define DIN 512
#define EDIM_ 256
#define HID 1024
#define NEXP 4
#define RK 768

typedef __attribute__((ext_vector_type(8))) short short8;
typedef __attribute__((ext_vector_type(4))) float f32x4;
typedef __attribute__((ext_vector_type(4))) unsigned short u16x4;

typedef __attribute__((address_space(1))) const void gv_t;
typedef __attribute__((address_space(3))) void lv_t;

// ---- workspace layout (bytes) ----
#define OFF_COUNTS 0
#define OFF_GVAL   256
#define OFF_PERM   (OFF_GVAL + 131072)
#define OFF_PART   (OFF_PERM + 524288)
#define OFF_WB1    (OFF_PART + 40960)
#define OFF_WB2    (OFF_WB1 + 4194304)
// total ~8.7 MB

__device__ __forceinline__ unsigned short f2bf(float f) {
  unsigned u = __float_as_uint(f);
  u = (u + 0x7fffu + ((u >> 16) & 1u)) >> 16;
  return (unsigned short)u;
}

__device__ __forceinline__ f32x4 mfma16(short8 a, short8 b, f32x4 c) {
  return __builtin_amdgcn_mfma_f32_16x16x32_bf16(a, b, c, 0, 0, 0);
}

// ---------------- weight convert f32 -> bf16 ----------------
__global__ __launch_bounds__(256) void cvt_kernel(const float4* __restrict__ w1,
                                                  const float4* __restrict__ w2,
                                                  unsigned short* __restrict__ wb1,
                                                  unsigned short* __restrict__ wb2) {
  const int i = blockIdx.x * 256 + threadIdx.x;  // 0..524287 covers 2097152 elems
  float4 a = w1[i];
  float4 b = w2[i];
  u16x4 pa, pb;
  pa[0] = f2bf(a.x); pa[1] = f2bf(a.y); pa[2] = f2bf(a.z); pa[3] = f2bf(a.w);
  pb[0] = f2bf(b.x); pb[1] = f2bf(b.y); pb[2] = f2bf(b.z); pb[3] = f2bf(b.w);
  *(u16x4*)(wb1 + (size_t)i * 4) = pa;
  *(u16x4*)(wb2 + (size_t)i * 4) = pb;
}

// ---------------- router: logits, softmax, gate, scatter, loss partials ----------------
__global__ __launch_bounds__(256) void router_kernel(const float* __restrict__ x,
                                                     const float* __restrict__ emb,
                                                     const float* __restrict__ rw,
                                                     float* __restrict__ gval,
                                                     unsigned* __restrict__ counts,
                                                     unsigned* __restrict__ perm,
                                                     double* __restrict__ partials) {
  __shared__ float rws[RK * 4];
  __shared__ double vals[64][5];
  __shared__ int sgid[64];
  for (int i = threadIdx.x; i < RK * 4; i += 256) rws[i] = rw[i];
  __syncthreads();
  const int wave = threadIdx.x >> 6, lane = threadIdx.x & 63;
  for (int it = 0; it < 16; it++) {
    const int sl = wave * 16 + it;
    const int t = blockIdx.x * 64 + sl;
    double a0 = 0, a1 = 0, a2 = 0, a3 = 0;
    const float* er = emb + (size_t)t * EDIM_;
    const float* xr = x + (size_t)t * DIN;
    for (int j = lane; j < RK; j += 64) {
      float v = (j < EDIM_) ? er[j] : xr[j - EDIM_];
      const float* w = rws + j * 4;
      a0 += (double)v * w[0]; a1 += (double)v * w[1];
      a2 += (double)v * w[2]; a3 += (double)v * w[3];
    }
    for (int off = 32; off > 0; off >>= 1) {
      a0 += __shfl_down(a0, off); a1 += __shfl_down(a1, off);
      a2 += __shfl_down(a2, off); a3 += __shfl_down(a3, off);
    }
    if (lane == 0) {
      double l[4] = {a0, a1, a2, a3};
      int bi = 0; double mx = l[0];
      for (int k = 1; k < 4; k++) if (l[k] > mx) { mx = l[k]; bi = k; }
      double p[4], s = 0;
      for (int k = 0; k < 4; k++) { p[k] = exp(l[k] - mx); s += p[k]; }
      double inv = 1.0 / s, sq = 0, sp = 0;
      for (int k = 0; k < 4; k++) { p[k] *= inv; sq += p[k] * p[k]; sp += p[k]; }
      gval[t] = (float)p[bi];
      sgid[sl] = bi;
      double* vv = vals[sl];
      vv[0] = p[0]; vv[1] = p[1]; vv[2] = p[2]; vv[3] = p[3];
      vv[4] = sp / (sqrt(sq) + 1e-10);
    }
  }
  __syncthreads();
  if (threadIdx.x < 5) {
    double acc = 0;
    for (int k = 0; k < 64; k++) acc += vals[k][threadIdx.x];
    partials[(size_t)blockIdx.x * 5 + threadIdx.x] = acc;
  }
  if (threadIdx.x < 64) {  // wave 0: scatter 64 tokens
    const int e = sgid[threadIdx.x];
    const int t = blockIdx.x * 64 + threadIdx.x;
    for (int ei = 0; ei < NEXP; ei++) {
      unsigned long long mask = __ballot(e == ei);
      if (mask == 0ull) continue;
      const int leader = __ffsll((unsigned long long)mask) - 1;
      unsigned base = 0;
      if (lane == leader) base = atomicAdd(&counts[ei], (unsigned)__popcll(mask));
      base = __shfl(base, leader, 64);
      if (e == ei) {
        const int rank = __popcll(mask & ((1ull << lane) - 1ull));
        perm[(size_t)ei * NTOK + base + rank] = (unsigned)t;
      }
    }
  }
}

// ---------------- fused grouped expert FFN (pipelined) ----------------
// LDS: Xs [64][512]bf16 @0 (64KB)  Hs [64][128]bf16 @65536 (16KB)
//      Wb0 @81920 (32KB)  Wb1 @114688 (32KB)  idx @147456
#define LDS_HS 65536
#define LDS_W0 81920
#define LDS_W1B 114688
#define LDS_IDX 147456
#define LDS_TOTAL 147712

__global__ __launch_bounds__(512, 1) void ffn_kernel(
    const float* __restrict__ x,
    const float* __restrict__ b1, const float* __restrict__ b2,
    const unsigned short* __restrict__ wb1, const unsigned short* __restrict__ wb2,
    const unsigned* __restrict__ counts, const unsigned* __restrict__ perm,
    const float* __restrict__ gval, const double* __restrict__ partials,
    float* __restrict__ out) {
  extern __shared__ char smem[];
  char* Xs = smem;
  char* Hs = smem + LDS_HS;
  char* Wb0 = smem + LDS_W0;
  char* Wb1p = smem + LDS_W1B;
  unsigned* idxs = (unsigned*)(smem + LDS_IDX);

  const int tid = threadIdx.x;
  const int lane = tid & 63, wid = tid >> 6;
  const int wm = wid & 1, wn = wid >> 1;

  const unsigned c0 = counts[0], c1 = counts[1], c2 = counts[2], c3 = counts[3];
  const unsigned n0 = (c0 + 63u) >> 6, n1 = (c1 + 63u) >> 6, n2 = (c2 + 63u) >> 6, n3 = (c3 + 63u) >> 6;
  const unsigned bs1 = n0, bs2 = n0 + n1, bs3 = n0 + n1 + n2, total = bs3 + n3;

  // XCD-bijective swizzle for nwg=516: q=64, r=4
  const unsigned orig = blockIdx.x;
  const unsigned xcd = orig & 7u, jj0 = orig >> 3;
  const unsigned wg = (xcd < 4u ? xcd * 65u : 260u + (xcd - 4u) * 64u) + jj0;

  // loss finalize on wave 0 of original block 0 (no extra barriers needed)
  if (orig == 0u && wid == 0) {
    double s0 = 0, s1 = 0, s2 = 0, s3 = 0, s4 = 0;
    for (int k = lane; k < 512; k += 64) {
      const double* p = partials + (size_t)k * 5;
      s0 += p[0]; s1 += p[1]; s2 += p[2]; s3 += p[3]; s4 += p[4];
    }
    for (int off = 32; off > 0; off >>= 1) {
      s0 += __shfl_down(s0, off); s1 += __shfl_down(s1, off);
      s2 += __shfl_down(s2, off); s3 += __shfl_down(s3, off);
      s4 += __shfl_down(s4, off);
    }
    if (lane == 0) {
      double mean = (s0 + s1 + s2 + s3) * 0.25;
      double var = ((s0 - mean) * (s0 - mean) + (s1 - mean) * (s1 - mean) +
                    (s2 - mean) * (s2 - mean) + (s3 - mean) * (s3 - mean)) * 0.25;
      out[16777216] = (float)(s4 / (double)NTOK);
      out[16777217] = (float)(var / (mean * mean + 1e-10));
    }
  }

  if (wg >= total) return;
  int e; unsigned tb;
  if (wg >= bs3)      { e = 3; tb = bs3; }
  else if (wg >= bs2) { e = 2; tb = bs2; }
  else if (wg >= bs1) { e = 1; tb = bs1; }
  else                { e = 0; tb = 0;   }
  const unsigned cnt_e = (e == 0) ? c0 : (e == 1) ? c1 : (e == 2) ? c2 : c3;
  const unsigned trow0 = (wg - tb) * 64u;
  const int mcnt = (int)min(64u, cnt_e - trow0);

  const unsigned short* w1e = wb1 + (size_t)e * HID * DIN;
  const unsigned short* w2e = wb2 + (size_t)e * DIN * HID;

  // staging lambdas: 32KB tile each, 4 x global_load_lds(16B) per thread
  auto issueW1 = [&](int hcn, int kt, char* dst) {
#pragma unroll
    for (int p = 0; p < 4; p++) {
      const unsigned L = (unsigned)(p * 8192 + wid * 1024 + lane * 16);
      const unsigned nn = L >> 8, cc = L & 255u;
      const unsigned sc = cc ^ ((nn & 7u) << 4);
      const char* g = (const char*)(w1e + (size_t)(hcn * 128 + (int)nn) * DIN) + kt * 256 + (int)sc;
      __builtin_amdgcn_global_load_lds((gv_t*)g, (lv_t*)(dst + p * 8192 + wid * 1024), 16, 0, 0);
    }
  };
  auto issueW2 = [&](int hcn, int idx, char* dst) {  // idx: bit0=nt, bit1=kt
    const int nt = idx & 1, kt = idx >> 1;
#pragma unroll
    for (int p = 0; p < 4; p++) {
      const unsigned L = (unsigned)(p * 8192 + wid * 1024 + lane * 16);
      const unsigned nn = L >> 7, cc = L & 127u;
      const unsigned sc = cc ^ ((nn & 7u) << 4);
      const char* g = (const char*)(w2e + (size_t)(nt * 256 + (int)nn) * HID) + hcn * 256 + kt * 128 + (int)sc;
      __builtin_amdgcn_global_load_lds((gv_t*)g, (lv_t*)(dst + p * 8192 + wid * 1024), 16, 0, 0);
    }
  };

  // b1 preload (16 scalars)
  float b1v[8][2];
#pragma unroll
  for (int hc = 0; hc < 8; hc++)
#pragma unroll
    for (int nf = 0; nf < 2; nf++)
      b1v[hc][nf] = b1[e * HID + hc * 128 + wn * 32 + nf * 16 + (lane & 15)];

  issueW1(0, 0, Wb0);  // prefetch tile 0

  if (tid < 64) {
    int rr = tid < mcnt ? tid : (mcnt - 1);
    idxs[tid] = perm[(size_t)e * NTOK + trow0 + rr];
  }
  __syncthreads();

  // stage X tile: gather f32 -> bf16 -> swizzled LDS
  {
    const int r = tid >> 3, q = tid & 7;
    const float* src = x + (size_t)idxs[r] * DIN;
    const unsigned sw = (unsigned)((r & 7) << 4);
#pragma unroll
    for (int i = 0; i < 8; i++) {
      const int cc0 = i * 64 + q * 8;
      float4 f0 = *(const float4*)(src + cc0);
      float4 f1 = *(const float4*)(src + cc0 + 4);
      short8 v;
      v[0] = (short)f2bf(f0.x); v[1] = (short)f2bf(f0.y);
      v[2] = (short)f2bf(f0.z); v[3] = (short)f2bf(f0.w);
      v[4] = (short)f2bf(f1.x); v[5] = (short)f2bf(f1.y);
      v[6] = (short)f2bf(f1.z); v[7] = (short)f2bf(f1.w);
      *(short8*)(Xs + r * 1024 + ((unsigned)(cc0 * 2) ^ sw)) = v;
    }
  }

  f32x4 acc2[2][8];
#pragma unroll
  for (int i = 0; i < 2; i++)
#pragma unroll
    for (int j = 0; j < 8; j++) acc2[i][j] = (f32x4){0.f, 0.f, 0.f, 0.f};

  for (int hc = 0; hc < 8; hc++) {
    f32x4 acc1[2][2];
#pragma unroll
    for (int i = 0; i < 2; i++)
#pragma unroll
      for (int j = 0; j < 2; j++) acc1[i][j] = (f32x4){0.f, 0.f, 0.f, 0.f};

#pragma unroll
    for (int t = 0; t < 8; t++) {
      const int i = hc * 8 + t;
      char* dst = ((i + 1) & 1) ? Wb1p : Wb0;
      // issue prefetch of tile i+1 (except very last tile), counted wait
      if (t < 7) {
        const int tn = t + 1;
        if (tn < 4) issueW1(hc, tn, dst); else issueW2(hc, tn - 4, dst);
        asm volatile("s_waitcnt vmcnt(4)" ::: "memory");
      } else if (hc < 7) {
        issueW1(hc + 1, 0, dst);
        asm volatile("s_waitcnt vmcnt(4)" ::: "memory");
      } else {
        asm volatile("s_waitcnt vmcnt(0)" ::: "memory");
      }
      __syncthreads();
      char* buf = (i & 1) ? Wb1p : Wb0;

      if (t < 4) {
        // GEMM1 k-tile t: acc1 += X[:, t*128..] * W1tile^T
#pragma unroll
        for (int s = 0; s < 4; s++) {
          short8 a[2], b[2];
          const int kb = t * 256 + s * 64 + 16 * (lane >> 4);
#pragma unroll
          for (int mf = 0; mf < 2; mf++) {
            const int r = wm * 32 + mf * 16 + (lane & 15);
            a[mf] = *(const short8*)(Xs + r * 1024 + (unsigned)(kb ^ ((r & 7) << 4)));
          }
          const int cb = s * 64 + 16 * (lane >> 4);
#pragma unroll
          for (int nf = 0; nf < 2; nf++) {
            const int nn = wn * 32 + nf * 16 + (lane & 15);
            b[nf] = *(const short8*)(buf + nn * 256 + (unsigned)(cb ^ ((nn & 7) << 4)));
          }
          __builtin_amdgcn_s_setprio(1);
          acc1[0][0] = mfma16(a[0], b[0], acc1[0][0]);
          acc1[0][1] = mfma16(a[0], b[1], acc1[0][1]);
          acc1[1][0] = mfma16(a[1], b[0], acc1[1][0]);
          acc1[1][1] = mfma16(a[1], b[1], acc1[1][1]);
          __builtin_amdgcn_s_setprio(0);
        }
        if (t == 3) {
          // bias + relu -> Hs (bf16, swizzled)
#pragma unroll
          for (int mf = 0; mf < 2; mf++)
#pragma unroll
            for (int nf = 0; nf < 2; nf++) {
              const int col = wn * 32 + nf * 16 + (lane & 15);
              const float bias = b1v[hc][nf];
#pragma unroll
              for (int bb = 0; bb < 4; bb++) {
                const int r = wm * 32 + mf * 16 + 4 * (lane >> 4) + bb;
                float v = acc1[mf][nf][bb] + bias;
                v = v > 0.f ? v : 0.f;
                *(unsigned short*)(Hs + r * 256 + (((unsigned)(col * 2)) ^ ((unsigned)(r & 7) << 4))) = f2bf(v);
              }
            }
        }
      } else {
        // GEMM2 tile: nt = (t-4)&1 selects n-half, kt = (t-4)>>1 selects k-half
        const int nt = (t - 4) & 1, kt = (t - 4) >> 1;
#pragma unroll
        for (int s = 0; s < 2; s++) {
          short8 a[2];
          const int kb = kt * 128 + s * 64 + 16 * (lane >> 4);
#pragma unroll
          for (int mf = 0; mf < 2; mf++) {
            const int r = wm * 32 + mf * 16 + (lane & 15);
            a[mf] = *(const short8*)(Hs + r * 256 + (unsigned)(kb ^ ((r & 7) << 4)));
          }
          const int cb = s * 64 + 16 * (lane >> 4);
          __builtin_amdgcn_s_setprio(1);
#pragma unroll
          for (int j = 0; j < 4; j++) {
            const int nl = wn * 64 + j * 16 + (lane & 15);
            short8 b = *(const short8*)(buf + nl * 128 + (unsigned)(cb ^ ((nl & 7) << 4)));
            acc2[0][nt * 4 + j] = mfma16(a[0], b, acc2[0][nt * 4 + j]);
            acc2[1][nt * 4 + j] = mfma16(a[1], b, acc2[1][nt * 4 + j]);
          }
          __builtin_amdgcn_s_setprio(0);
        }
      }
      __syncthreads();
    }
  }

  // epilogue: (y + b2) * gate -> out
  const float* b2e = b2 + e * DIN;
#pragma unroll
  for (int mf = 0; mf < 2; mf++)
#pragma unroll
    for (int bb = 0; bb < 4; bb++) {
      const int rt = wm * 32 + mf * 16 + 4 * (lane >> 4) + bb;
      if (rt < mcnt) {
        const unsigned tok = idxs[rt];
        const float g = gval[tok];
        float* orow = out + (size_t)tok * DIN;
#pragma unroll
        for (int j = 0; j < 8; j++) {
          const int col = (j >> 2) * 256 + wn * 64 + (j & 3) * 16 + (lane & 15);
          orow[col] = (acc2[mf][j][bb] + b2e[col]) * g;
        }
      }
    }
}

extern "C" void kernel_launch(void* const* d_in, const int* in_sizes, int n_in,
                              void* d_out, int out_size, void* d_ws, size_t ws_size,
                              hipStream_t stream) {
  const float* x   = (const float*)d_in[0];
  const float* emb = (const float*)d_in[1];
  const float* rw  = (const float*)d_in[2];
  const float* w1  = (const float*)d_in[3];
  const float* b1  = (const float*)d_in[4];
  const float* w2  = (const float*)d_in[5];
  const float* b2  = (const float*)d_in[6];
  float* out = (float*)d_out;

  char* ws = (char*)d_ws;
  unsigned* counts = (unsigned*)(ws + OFF_COUNTS);
  float* gval = (float*)(ws + OFF_GVAL);
  unsigned* perm = (unsigned*)(ws + OFF_PERM);
  double* partials = (double*)(ws + OFF_PART);
  unsigned short* wb1 = (unsigned short*)(ws + OFF_WB1);
  unsigned short* wb2 = (unsigned short*)(ws + OFF_WB2);

  hipMemsetAsync(ws, 0, 256, stream);
  cvt_kernel<<<2048, 256, 0, stream>>>((const float4*)w1, (const float4*)w2, wb1, wb2);
  router_kernel<<<512, 256, 0, stream>>>(x, emb, rw, gval, counts, perm, partials);

  hipFuncSetAttribute((const void*)ffn_kernel, hipFuncAttributeMaxDynamicSharedMemorySize, LDS_TOTAL);
  ffn_kernel<<<516, 512, LDS_TOTAL, stream>>>(x, b1, b2, wb1, wb2, counts, perm, gval, partials, out);
}

// Round 3
// 218.051 us; speedup vs baseline: 1.4586x; 1.4586x over previous
//
#include <hip/hip_runtime.h>
#include <hip/hip_bf16.h>
#include <cstdint>
#include <cstddef>

#define NTOK 32768
#define DIN 512
#define EDIM_ 256
#define HID 1024
#define NEXP 4
#define RK 768

typedef __attribute__((ext_vector_type(8))) short short8;
typedef __attribute__((ext_vector_type(4))) float f32x4;
typedef __attribute__((ext_vector_type(4))) unsigned short u16x4;

typedef __attribute__((address_space(1))) const void gv_t;
typedef __attribute__((address_space(3))) void lv_t;

// ---- workspace layout (bytes) ----
#define OFF_COUNTS 0
#define OFF_GVAL   256
#define OFF_PERM   (OFF_GVAL + 131072)
#define OFF_PART   (OFF_PERM + 524288)
#define OFF_WB1    (OFF_PART + 40960)
#define OFF_WB2    (OFF_WB1 + 4194304)

__device__ __forceinline__ unsigned short f2bf(float f) {
  unsigned u = __float_as_uint(f);
  u = (u + 0x7fffu + ((u >> 16) & 1u)) >> 16;
  return (unsigned short)u;
}

__device__ __forceinline__ f32x4 mfma16(short8 a, short8 b, f32x4 c) {
  return __builtin_amdgcn_mfma_f32_16x16x32_bf16(a, b, c, 0, 0, 0);
}

// ---------------- router + cvt fused ----------------
__global__ __launch_bounds__(256) void router_kernel(const float* __restrict__ x,
                                                     const float* __restrict__ emb,
                                                     const float* __restrict__ rw,
                                                     float* __restrict__ gval,
                                                     unsigned* __restrict__ counts,
                                                     unsigned* __restrict__ perm,
                                                     double* __restrict__ partials,
                                                     const float4* __restrict__ w1f,
                                                     const float4* __restrict__ w2f,
                                                     unsigned short* __restrict__ wb1,
                                                     unsigned short* __restrict__ wb2) {
  // --- weight cvt: 4 float4-pairs per thread (grid 512 x 256 x 4 = 524288) ---
#pragma unroll
  for (int c = 0; c < 4; c++) {
    const int i = blockIdx.x * 1024 + c * 256 + threadIdx.x;
    float4 a = w1f[i];
    float4 b = w2f[i];
    u16x4 pa, pb;
    pa[0] = f2bf(a.x); pa[1] = f2bf(a.y); pa[2] = f2bf(a.z); pa[3] = f2bf(a.w);
    pb[0] = f2bf(b.x); pb[1] = f2bf(b.y); pb[2] = f2bf(b.z); pb[3] = f2bf(b.w);
    *(u16x4*)(wb1 + (size_t)i * 4) = pa;
    *(u16x4*)(wb2 + (size_t)i * 4) = pb;
  }

  // --- router ---
  __shared__ float rws[4][772];   // transposed + padded: conflict-free
  __shared__ double vals[64][5];
  __shared__ int sgid[64];
  for (int idx = threadIdx.x; idx < RK * 4; idx += 256) {
    const int j = idx >> 2, k = idx & 3;
    rws[k][j] = rw[idx];
  }
  __syncthreads();
  const int wave = threadIdx.x >> 6, lane = threadIdx.x & 63;
  for (int it = 0; it < 16; it++) {
    const int sl = wave * 16 + it;
    const int t = blockIdx.x * 64 + sl;
    double a0 = 0, a1 = 0, a2 = 0, a3 = 0;
    const float* er = emb + (size_t)t * EDIM_;
    const float* xr = x + (size_t)t * DIN;
    for (int j = lane; j < RK; j += 64) {
      float v = (j < EDIM_) ? er[j] : xr[j - EDIM_];
      a0 += (double)v * rws[0][j]; a1 += (double)v * rws[1][j];
      a2 += (double)v * rws[2][j]; a3 += (double)v * rws[3][j];
    }
    for (int off = 32; off > 0; off >>= 1) {
      a0 += __shfl_down(a0, off); a1 += __shfl_down(a1, off);
      a2 += __shfl_down(a2, off); a3 += __shfl_down(a3, off);
    }
    if (lane == 0) {
      double l[4] = {a0, a1, a2, a3};
      int bi = 0; double mx = l[0];
      for (int k = 1; k < 4; k++) if (l[k] > mx) { mx = l[k]; bi = k; }
      double p[4], s = 0;
      for (int k = 0; k < 4; k++) { p[k] = exp(l[k] - mx); s += p[k]; }
      double inv = 1.0 / s, sq = 0, sp = 0;
      for (int k = 0; k < 4; k++) { p[k] *= inv; sq += p[k] * p[k]; sp += p[k]; }
      gval[t] = (float)p[bi];
      sgid[sl] = bi;
      double* vv = vals[sl];
      vv[0] = p[0]; vv[1] = p[1]; vv[2] = p[2]; vv[3] = p[3];
      vv[4] = sp / (sqrt(sq) + 1e-10);
    }
  }
  __syncthreads();
  if (threadIdx.x < 5) {
    double acc = 0;
    for (int k = 0; k < 64; k++) acc += vals[k][threadIdx.x];
    partials[(size_t)blockIdx.x * 5 + threadIdx.x] = acc;
  }
  if (threadIdx.x < 64) {  // wave 0: scatter 64 tokens
    const int e = sgid[threadIdx.x];
    const int t = blockIdx.x * 64 + threadIdx.x;
    for (int ei = 0; ei < NEXP; ei++) {
      unsigned long long mask = __ballot(e == ei);
      if (mask == 0ull) continue;
      const int leader = __ffsll((unsigned long long)mask) - 1;
      unsigned base = 0;
      if (lane == leader) base = atomicAdd(&counts[ei], (unsigned)__popcll(mask));
      base = __shfl(base, leader, 64);
      if (e == ei) {
        const int rank = __popcll(mask & ((1ull << lane) - 1ull));
        perm[(size_t)ei * NTOK + base + rank] = (unsigned)t;
      }
    }
  }
}

// ---------------- fused grouped expert FFN: raw-barrier 3-deep pipeline ----------------
// LDS: Xs [64][512]bf16 @0 (64KB, swz (r&7)<<4)
//      Hs [64][128]bf16 @65536 (16KB, swz)
//      b1s f32[1024]    @81920 (4KB)
//      buf[4] 16KB each @86016 (64KB)   -> total 151552
#define LDS_HS 65536
#define LDS_B1 81920
#define LDS_BUF 86016
#define LDS_TOTAL 151552

__global__ __launch_bounds__(512, 1) void ffn_kernel(
    const float* __restrict__ x,
    const float* __restrict__ b1, const float* __restrict__ b2,
    const unsigned short* __restrict__ wb1, const unsigned short* __restrict__ wb2,
    const unsigned* __restrict__ counts, const unsigned* __restrict__ perm,
    const float* __restrict__ gval, const double* __restrict__ partials,
    float* __restrict__ out) {
  extern __shared__ char smem[];
  char* Xs = smem;
  char* Hs = smem + LDS_HS;
  float* b1s = (float*)(smem + LDS_B1);
  char* bufs = smem + LDS_BUF;

  const int tid = threadIdx.x;
  const int lane = tid & 63, wid = tid >> 6;
  const int wm = wid & 1, wn = wid >> 1;
  const int lq = 16 * (lane >> 4);

  const unsigned c0 = counts[0], c1 = counts[1], c2 = counts[2], c3 = counts[3];
  const unsigned n0 = (c0 + 63u) >> 6, n1 = (c1 + 63u) >> 6, n2 = (c2 + 63u) >> 6, n3 = (c3 + 63u) >> 6;
  const unsigned bs1 = n0, bs2 = n0 + n1, bs3 = n0 + n1 + n2, total = bs3 + n3;

  // XCD-bijective swizzle for nwg=516 (q=64, r=4): clusters same-expert tiles per XCD L2
  const unsigned orig = blockIdx.x;
  const unsigned xcd = orig & 7u, jj0 = orig >> 3;
  const unsigned wg = (xcd < 4u ? xcd * 65u : 260u + (xcd - 4u) * 64u) + jj0;

  // loss finalize (block 0, wave 0) — before any DMA is issued
  if (orig == 0u && wid == 0) {
    double s0 = 0, s1 = 0, s2 = 0, s3 = 0, s4 = 0;
    for (int k = lane; k < 512; k += 64) {
      const double* p = partials + (size_t)k * 5;
      s0 += p[0]; s1 += p[1]; s2 += p[2]; s3 += p[3]; s4 += p[4];
    }
    for (int off = 32; off > 0; off >>= 1) {
      s0 += __shfl_down(s0, off); s1 += __shfl_down(s1, off);
      s2 += __shfl_down(s2, off); s3 += __shfl_down(s3, off);
      s4 += __shfl_down(s4, off);
    }
    if (lane == 0) {
      double mean = (s0 + s1 + s2 + s3) * 0.25;
      double var = ((s0 - mean) * (s0 - mean) + (s1 - mean) * (s1 - mean) +
                    (s2 - mean) * (s2 - mean) + (s3 - mean) * (s3 - mean)) * 0.25;
      out[16777216] = (float)(s4 / (double)NTOK);
      out[16777217] = (float)(var / (mean * mean + 1e-10));
    }
  }

  if (wg >= total) return;
  int e; unsigned tb;
  if (wg >= bs3)      { e = 3; tb = bs3; }
  else if (wg >= bs2) { e = 2; tb = bs2; }
  else if (wg >= bs1) { e = 1; tb = bs1; }
  else                { e = 0; tb = 0;   }
  const unsigned cnt_e = (e == 0) ? c0 : (e == 1) ? c1 : (e == 2) ? c2 : c3;
  const unsigned trow0 = (wg - tb) * 64u;
  const int mcnt = (int)min(64u, cnt_e - trow0);
  const size_t pbase = (size_t)e * NTOK + trow0;

  const unsigned short* w1e = wb1 + (size_t)e * HID * DIN;
  const unsigned short* w2e = wb2 + (size_t)e * DIN * HID;

  // 16KB half-tile staging: 2 x global_load_lds(16B) per thread
  auto issueW1 = [&](int hcn, int ht, char* dst) {
#pragma unroll
    for (int p = 0; p < 2; p++) {
      const unsigned L = (unsigned)(p * 8192 + tid * 16);
      const unsigned nn = L >> 7, cc = L & 127u;
      const unsigned sc = cc ^ ((nn & 7u) << 4);
      const char* g = (const char*)(w1e + (size_t)(hcn * 128 + (int)nn) * DIN) + ht * 128 + (int)sc;
      __builtin_amdgcn_global_load_lds((gv_t*)g, (lv_t*)(dst + p * 8192 + wid * 1024), 16, 0, 0);
    }
  };
  auto issueW2 = [&](int hcn, int h2, char* dst) {
    const int kt = h2 & 1, ntile = h2 >> 1;
#pragma unroll
    for (int p = 0; p < 2; p++) {
      const unsigned L = (unsigned)(p * 8192 + tid * 16);
      const unsigned nn = L >> 7, cc = L & 127u;
      const unsigned sc = cc ^ ((nn & 7u) << 4);
      const char* g = (const char*)(w2e + (size_t)(ntile * 128 + (int)nn) * HID) + hcn * 256 + kt * 128 + (int)sc;
      __builtin_amdgcn_global_load_lds((gv_t*)g, (lv_t*)(dst + p * 8192 + wid * 1024), 16, 0, 0);
    }
  };

  // stage b1 (1024 f32) into LDS
  b1s[tid] = b1[e * HID + tid];
  b1s[tid + 512] = b1[e * HID + 512 + tid];

  // stage X tile: gather f32 -> bf16 -> swizzled LDS (rows clamp to mcnt-1)
  {
    const int r = tid >> 3, q = tid & 7;
    const unsigned tok = perm[pbase + (unsigned)(r < mcnt ? r : mcnt - 1)];
    const float* src = x + (size_t)tok * DIN;
    const unsigned sw = (unsigned)((r & 7) << 4);
#pragma unroll
    for (int i = 0; i < 8; i++) {
      const int cc0 = i * 64 + q * 8;
      float4 f0 = *(const float4*)(src + cc0);
      float4 f1 = *(const float4*)(src + cc0 + 4);
      short8 v;
      v[0] = (short)f2bf(f0.x); v[1] = (short)f2bf(f0.y);
      v[2] = (short)f2bf(f0.z); v[3] = (short)f2bf(f0.w);
      v[4] = (short)f2bf(f1.x); v[5] = (short)f2bf(f1.y);
      v[6] = (short)f2bf(f1.z); v[7] = (short)f2bf(f1.w);
      *(short8*)(Xs + r * 1024 + ((unsigned)(cc0 * 2) ^ sw)) = v;
    }
  }
  asm volatile("s_waitcnt lgkmcnt(0)" ::: "memory");  // LDS writes visible before first barrier

  // prologue: prefetch half-tiles 0,1,2 (oldest-first)
  issueW1(0, 0, bufs);
  issueW1(0, 1, bufs + 16384);
  issueW1(0, 2, bufs + 32768);

  f32x4 acc2[2][8];
#pragma unroll
  for (int i = 0; i < 2; i++)
#pragma unroll
    for (int j = 0; j < 8; j++) acc2[i][j] = (f32x4){0.f, 0.f, 0.f, 0.f};

  for (int hc = 0; hc < 8; ++hc) {
    f32x4 acc1[2][2];
#pragma unroll
    for (int i = 0; i < 2; i++)
#pragma unroll
      for (int j = 0; j < 2; j++) acc1[i][j] = (f32x4){0.f, 0.f, 0.f, 0.f};

    // ---- 8 W1 half-tiles: [128n][64k], k = ht*64.. ----
#pragma unroll
    for (int ht = 0; ht < 8; ++ht) {
      asm volatile("s_waitcnt vmcnt(4)" ::: "memory");   // half-tile i landed (3-deep)
      __builtin_amdgcn_s_barrier();
      asm volatile("" ::: "memory");
      char* dst = bufs + ((ht + 3) & 3) * 16384;
      if (ht < 5) issueW1(hc, ht + 3, dst);
      else        issueW2(hc, ht - 5, dst);
      const char* buf = bufs + (ht & 3) * 16384;
#pragma unroll
      for (int sk = 0; sk < 2; ++sk) {
        short8 a[2], b[2];
#pragma unroll
        for (int mf = 0; mf < 2; ++mf) {
          const int r = wm * 32 + mf * 16 + (lane & 15);
          a[mf] = *(const short8*)(Xs + r * 1024 +
                   ((unsigned)(ht * 128 + sk * 64 + lq) ^ ((unsigned)(r & 7) << 4)));
        }
#pragma unroll
        for (int f = 0; f < 2; ++f) {
          const int nl = wn * 32 + f * 16 + (lane & 15);
          b[f] = *(const short8*)(buf + nl * 128 +
                  ((unsigned)(sk * 64 + lq) ^ ((unsigned)(nl & 7) << 4)));
        }
        __builtin_amdgcn_s_setprio(1);
        acc1[0][0] = mfma16(a[0], b[0], acc1[0][0]);
        acc1[0][1] = mfma16(a[0], b[1], acc1[0][1]);
        acc1[1][0] = mfma16(a[1], b[0], acc1[1][0]);
        acc1[1][1] = mfma16(a[1], b[1], acc1[1][1]);
        __builtin_amdgcn_s_setprio(0);
      }
    }

    // ---- bias + relu -> Hs (bf16, swizzled) ----
#pragma unroll
    for (int mf = 0; mf < 2; ++mf)
#pragma unroll
      for (int nf = 0; nf < 2; ++nf) {
        const int col = wn * 32 + nf * 16 + (lane & 15);
        const float bias = b1s[hc * 128 + col];
#pragma unroll
        for (int bb = 0; bb < 4; ++bb) {
          const int r = wm * 32 + mf * 16 + 4 * (lane >> 4) + bb;
          float v = acc1[mf][nf][bb] + bias;
          v = v > 0.f ? v : 0.f;
          *(unsigned short*)(Hs + r * 256 +
            (((unsigned)(col * 2)) ^ ((unsigned)(r & 7) << 4))) = f2bf(v);
        }
      }
    asm volatile("s_waitcnt lgkmcnt(0)" ::: "memory");  // Hs visible before next barrier

    // ---- 8 W2 half-tiles: [128n][64k] ----
#pragma unroll
    for (int h2 = 0; h2 < 8; ++h2) {
      if (h2 == 6) {
        if (hc == 7) asm volatile("s_waitcnt vmcnt(2)" ::: "memory");
        else         asm volatile("s_waitcnt vmcnt(4)" ::: "memory");
      } else if (h2 == 7) {
        if (hc == 7) asm volatile("s_waitcnt vmcnt(0)" ::: "memory");
        else         asm volatile("s_waitcnt vmcnt(4)" ::: "memory");
      } else {
        asm volatile("s_waitcnt vmcnt(4)" ::: "memory");
      }
      __builtin_amdgcn_s_barrier();
      asm volatile("" ::: "memory");
      char* dst = bufs + ((h2 + 3) & 3) * 16384;
      if (h2 < 5)      issueW2(hc, h2 + 3, dst);
      else if (hc < 7) issueW1(hc + 1, h2 - 5, dst);
      const char* buf = bufs + (h2 & 3) * 16384;
      const int kt = h2 & 1, ntile = h2 >> 1;
#pragma unroll
      for (int sk = 0; sk < 2; ++sk) {
        short8 a[2], b[2];
#pragma unroll
        for (int mf = 0; mf < 2; ++mf) {
          const int r = wm * 32 + mf * 16 + (lane & 15);
          a[mf] = *(const short8*)(Hs + r * 256 +
                   ((unsigned)(kt * 128 + sk * 64 + lq) ^ ((unsigned)(r & 7) << 4)));
        }
#pragma unroll
        for (int f = 0; f < 2; ++f) {
          const int nl = wn * 32 + f * 16 + (lane & 15);
          b[f] = *(const short8*)(buf + nl * 128 +
                  ((unsigned)(sk * 64 + lq) ^ ((unsigned)(nl & 7) << 4)));
        }
        __builtin_amdgcn_s_setprio(1);
        acc2[0][ntile * 2 + 0] = mfma16(a[0], b[0], acc2[0][ntile * 2 + 0]);
        acc2[0][ntile * 2 + 1] = mfma16(a[0], b[1], acc2[0][ntile * 2 + 1]);
        acc2[1][ntile * 2 + 0] = mfma16(a[1], b[0], acc2[1][ntile * 2 + 0]);
        acc2[1][ntile * 2 + 1] = mfma16(a[1], b[1], acc2[1][ntile * 2 + 1]);
        __builtin_amdgcn_s_setprio(0);
      }
    }
  }

  // epilogue: (y + b2) * gate -> out   (col = (jj>>1)*128 + wn*32 + (jj&1)*16 + lane15)
  const float* b2e = b2 + e * DIN;
#pragma unroll
  for (int mf = 0; mf < 2; ++mf)
#pragma unroll
    for (int bb = 0; bb < 4; ++bb) {
      const int rt = wm * 32 + mf * 16 + 4 * (lane >> 4) + bb;
      if (rt < mcnt) {
        const unsigned tok = perm[pbase + rt];
        const float g = gval[tok];
        float* orow = out + (size_t)tok * DIN;
#pragma unroll
        for (int jj = 0; jj < 8; ++jj) {
          const int col = (jj >> 1) * 128 + wn * 32 + (jj & 1) * 16 + (lane & 15);
          orow[col] = (acc2[mf][jj][bb] + b2e[col]) * g;
        }
      }
    }
}

extern "C" void kernel_launch(void* const* d_in, const int* in_sizes, int n_in,
                              void* d_out, int out_size, void* d_ws, size_t ws_size,
                              hipStream_t stream) {
  const float* x   = (const float*)d_in[0];
  const float* emb = (const float*)d_in[1];
  const float* rw  = (const float*)d_in[2];
  const float* w1  = (const float*)d_in[3];
  const float* b1  = (const float*)d_in[4];
  const float* w2  = (const float*)d_in[5];
  const float* b2  = (const float*)d_in[6];
  float* out = (float*)d_out;

  char* ws = (char*)d_ws;
  unsigned* counts = (unsigned*)(ws + OFF_COUNTS);
  float* gval = (float*)(ws + OFF_GVAL);
  unsigned* perm = (unsigned*)(ws + OFF_PERM);
  double* partials = (double*)(ws + OFF_PART);
  unsigned short* wb1 = (unsigned short*)(ws + OFF_WB1);
  unsigned short* wb2 = (unsigned short*)(ws + OFF_WB2);

  hipMemsetAsync(ws, 0, 256, stream);
  router_kernel<<<512, 256, 0, stream>>>(x, emb, rw, gval, counts, perm, partials,
                                         (const float4*)w1, (const float4*)w2, wb1, wb2);

  hipFuncSetAttribute((const void*)ffn_kernel, hipFuncAttributeMaxDynamicSharedMemorySize, LDS_TOTAL);
  ffn_kernel<<<516, 512, LDS_TOTAL, stream>>>(x, b1, b2, wb1, wb2, counts, perm, gval, partials, out);
}